// Round 1
// baseline (10439.901 us; speedup 1.0000x reference)
//
#include <hip/hip_runtime.h>
#include <cstdint>
#include <cstddef>

#define VSZ 32000
#define ED  512
#define HD  512
#define SQ  128
#define BA  64
#define INW 1024
#define NG  1536

typedef __attribute__((ext_vector_type(8))) short sh8;
typedef __attribute__((ext_vector_type(4))) float f32x4;

__device__ inline unsigned short f2bf(float f) {
  unsigned int u = __float_as_uint(f);
  u += 0x7fffu + ((u >> 16) & 1u);
  return (unsigned short)(u >> 16);
}

// ---------------- pre-projection: XG[m, 0:1536] = emb[x[m]] @ {Wr,Wz,Wh}[:, :512]^T + bias ----
__global__ __launch_bounds__(256) void proj_kernel(
    const int* __restrict__ x, const float* __restrict__ emb,
    const float* __restrict__ Wr, const float* __restrict__ Br,
    const float* __restrict__ Wz, const float* __restrict__ Bz,
    const float* __restrict__ Wh, const float* __restrict__ Bh,
    float* __restrict__ XG)
{
  __shared__ float As[32][68];
  __shared__ float Bs[32][68];
  const int tid = threadIdx.x;
  const int bx = blockIdx.x;   // N tile: 0..23
  const int by = blockIdx.y;   // M tile: 0..127
  const int tx = tid & 15, ty = tid >> 4;
  float acc[4][4] = {{0.f}};

  for (int k0 = 0; k0 < ED; k0 += 32) {
    #pragma unroll
    for (int it = 0; it < 2; ++it) {
      const int s   = tid + it * 256;
      const int row = s >> 3;
      const int c4  = (s & 7) << 2;
      {
        const int m    = by * 64 + row;
        const int vrow = x[m];
        const float4 v = *(const float4*)(emb + (size_t)vrow * ED + k0 + c4);
        As[c4+0][row] = v.x; As[c4+1][row] = v.y; As[c4+2][row] = v.z; As[c4+3][row] = v.w;
      }
      {
        const int j  = bx * 64 + row;
        const int g  = j >> 9, jj = j & 511;
        const float* wrow = (g == 0 ? Wr : (g == 1 ? Wz : Wh)) + (size_t)jj * INW;
        const float4 v = *(const float4*)(wrow + k0 + c4);
        Bs[c4+0][row] = v.x; Bs[c4+1][row] = v.y; Bs[c4+2][row] = v.z; Bs[c4+3][row] = v.w;
      }
    }
    __syncthreads();
    #pragma unroll
    for (int k = 0; k < 32; ++k) {
      const float4 a4 = *(const float4*)&As[k][ty << 2];
      const float4 b4 = *(const float4*)&Bs[k][tx << 2];
      const float av[4] = {a4.x, a4.y, a4.z, a4.w};
      const float bv[4] = {b4.x, b4.y, b4.z, b4.w};
      #pragma unroll
      for (int i = 0; i < 4; ++i)
        #pragma unroll
        for (int j = 0; j < 4; ++j)
          acc[i][j] += av[i] * bv[j];
    }
    __syncthreads();
  }
  #pragma unroll
  for (int j = 0; j < 4; ++j) {
    const int jc = bx * 64 + (tx << 2) + j;
    const int g = jc >> 9, jj = jc & 511;
    const float bias = (g == 0 ? Br : (g == 1 ? Bz : Bh))[jj];
    #pragma unroll
    for (int i = 0; i < 4; ++i) {
      const int m = by * 64 + (ty << 2) + i;
      XG[(size_t)m * NG + jc] = acc[i][j] + bias;
    }
  }
}

// ---------------- step phase A: r,z gates. lane = gate column, 4 batch rows per wave ----------
// kk in [0,1024): kk<512 -> r column, else z column. Writes u_T[m][b] = r*h, z_N[b][j].
__global__ __launch_bounds__(64) void gate_rz_kernel(
    const float* __restrict__ XG, const float* __restrict__ h_T,
    const float* __restrict__ Wr, const float* __restrict__ Wz,
    float* __restrict__ u_T, float* __restrict__ z_N, int t)
{
  const int lane = threadIdx.x;            // 0..63
  const int kkg  = blockIdx.x >> 4;        // 0..15
  const int bg   = blockIdx.x & 15;        // b = bg*4 .. +4
  const int kk   = kkg * 64 + lane;        // 0..1023
  const int g    = kk >> 9;                // 0:r  1:z
  const int col  = kk & 511;
  const float* wrow = (g == 0 ? Wr : Wz) + (size_t)col * INW + ED; // recurrent half

  float acc[4];
  #pragma unroll
  for (int i = 0; i < 4; ++i)
    acc[i] = XG[(size_t)(t * BA + bg * 4 + i) * NG + kk];

  if (t > 0) {
    for (int m = 0; m < HD; m += 4) {
      const float4 w4 = *(const float4*)(wrow + m);
      const float wv[4] = {w4.x, w4.y, w4.z, w4.w};
      #pragma unroll
      for (int mm = 0; mm < 4; ++mm) {
        const float* hp = h_T + (m + mm) * BA + bg * 4;  // wave-uniform -> s_load
        const float h0 = hp[0], h1 = hp[1], h2 = hp[2], h3 = hp[3];
        acc[0] += wv[mm] * h0; acc[1] += wv[mm] * h1;
        acc[2] += wv[mm] * h2; acc[3] += wv[mm] * h3;
      }
    }
  }
  #pragma unroll
  for (int i = 0; i < 4; ++i) {
    const int b = bg * 4 + i;
    const float sg = 1.0f / (1.0f + __expf(-acc[i]));
    if (g == 0) {
      const float hp = (t > 0) ? h_T[col * BA + b] : 0.0f;
      u_T[col * BA + b] = sg * hp;
    } else {
      z_N[(size_t)b * HD + col] = sg;
    }
  }
}

// ---------------- step phase B: h_cand + combine. Writes h_T[j][b] and Habf (bf16 history) ----
__global__ __launch_bounds__(64) void gate_h_kernel(
    const float* __restrict__ XG, float* __restrict__ h_T,
    const float* __restrict__ Wh,
    const float* __restrict__ u_T, const float* __restrict__ z_N,
    unsigned short* __restrict__ Habf, int t)
{
  const int lane = threadIdx.x;
  const int jg   = blockIdx.x >> 4;   // 0..7
  const int bg   = blockIdx.x & 15;
  const int j    = jg * 64 + lane;    // 0..511
  const float* wrow = Wh + (size_t)j * INW + ED;

  float acc[4];
  #pragma unroll
  for (int i = 0; i < 4; ++i)
    acc[i] = XG[(size_t)(t * BA + bg * 4 + i) * NG + 1024 + j];

  for (int m = 0; m < HD; m += 4) {
    const float4 w4 = *(const float4*)(wrow + m);
    const float wv[4] = {w4.x, w4.y, w4.z, w4.w};
    #pragma unroll
    for (int mm = 0; mm < 4; ++mm) {
      const float* up = u_T + (m + mm) * BA + bg * 4;  // wave-uniform -> s_load
      const float u0 = up[0], u1 = up[1], u2 = up[2], u3 = up[3];
      acc[0] += wv[mm] * u0; acc[1] += wv[mm] * u1;
      acc[2] += wv[mm] * u2; acc[3] += wv[mm] * u3;
    }
  }
  #pragma unroll
  for (int i = 0; i < 4; ++i) {
    const int b = bg * 4 + i;
    const float z  = z_N[(size_t)b * HD + j];
    const float hp = (t > 0) ? h_T[j * BA + b] : 0.0f;
    const float e  = __expf(2.0f * acc[i]);        // tanh via 1 - 2/(e^{2x}+1), inf-safe
    const float hc = 1.0f - 2.0f / (e + 1.0f);
    const float hn = z * hp + (1.0f - z) * hc;
    h_T[j * BA + b] = hn;
    Habf[(size_t)(t * BA + b) * HD + j] = f2bf(hn);
  }
}

// ---------------- final output GEMM: Y = Habf @ W^T + b  (bf16 MFMA, fp32 out) ----------------
__global__ __launch_bounds__(256) void out_gemm_kernel(
    const unsigned short* __restrict__ A,  // 8192 x 512 bf16
    const float* __restrict__ Bw,          // 32000 x 512 f32
    const float* __restrict__ bias,        // 32000
    float* __restrict__ Y)                 // 8192 x 32000
{
  __shared__ unsigned short As[128 * 32];
  __shared__ unsigned short Bs[128 * 32];
  const int bid = blockIdx.x;
  const int tn = bid % 250, tm = bid / 250;
  const int tid = threadIdx.x;
  const int wave = tid >> 6, lane = tid & 63;
  const int wm = wave >> 1, wn = wave & 1;
  const int l15 = lane & 15, lhi = lane >> 4;
  f32x4 acc[4][4] = {};

  for (int k0 = 0; k0 < 512; k0 += 32) {
    #pragma unroll
    for (int it = 0; it < 2; ++it) {
      const int ss  = tid + it * 256;
      const int row = ss >> 2;
      const int c8  = (ss & 3) << 3;
      *(uint4*)(As + row * 32 + c8) =
          *(const uint4*)(A + (size_t)(tm * 128 + row) * 512 + k0 + c8);
      const float4 b0 = *(const float4*)(Bw + (size_t)(tn * 128 + row) * 512 + k0 + c8);
      const float4 b1 = *(const float4*)(Bw + (size_t)(tn * 128 + row) * 512 + k0 + c8 + 4);
      union { unsigned short h[8]; uint4 u; } cv;
      cv.h[0] = f2bf(b0.x); cv.h[1] = f2bf(b0.y); cv.h[2] = f2bf(b0.z); cv.h[3] = f2bf(b0.w);
      cv.h[4] = f2bf(b1.x); cv.h[5] = f2bf(b1.y); cv.h[6] = f2bf(b1.z); cv.h[7] = f2bf(b1.w);
      *(uint4*)(Bs + row * 32 + c8) = cv.u;
    }
    __syncthreads();
    sh8 af[4], bfr[4];
    #pragma unroll
    for (int mi = 0; mi < 4; ++mi)
      af[mi] = *(const sh8*)(As + (wm * 64 + mi * 16 + l15) * 32 + lhi * 8);
    #pragma unroll
    for (int ni = 0; ni < 4; ++ni)
      bfr[ni] = *(const sh8*)(Bs + (wn * 64 + ni * 16 + l15) * 32 + lhi * 8);
    #pragma unroll
    for (int mi = 0; mi < 4; ++mi)
      #pragma unroll
      for (int ni = 0; ni < 4; ++ni)
        acc[mi][ni] = __builtin_amdgcn_mfma_f32_16x16x32_bf16(af[mi], bfr[ni], acc[mi][ni], 0, 0, 0);
    __syncthreads();
  }

  #pragma unroll
  for (int ni = 0; ni < 4; ++ni) {
    const int col = tn * 128 + wn * 64 + ni * 16 + l15;
    const float bv = bias[col];
    #pragma unroll
    for (int mi = 0; mi < 4; ++mi) {
      const int row0 = tm * 128 + wm * 64 + mi * 16 + lhi * 4;
      #pragma unroll
      for (int q = 0; q < 4; ++q)
        Y[(size_t)(row0 + q) * VSZ + col] = acc[mi][ni][q] + bv;
    }
  }
}

// ---------------- hT.T output: exactly the h_T[j][b] buffer ----------------------------------
__global__ void ht_copy_kernel(const float* __restrict__ h_T, float* __restrict__ dst) {
  const int i = blockIdx.x * 256 + threadIdx.x;  // 32768 total
  dst[i] = h_T[i];
}

extern "C" void kernel_launch(void* const* d_in, const int* in_sizes, int n_in,
                              void* d_out, int out_size, void* d_ws, size_t ws_size,
                              hipStream_t stream)
{
  const int*   x   = (const int*)  d_in[0];
  const float* emb = (const float*)d_in[1];
  const float* Wr  = (const float*)d_in[2];
  const float* Br  = (const float*)d_in[3];
  const float* Wz  = (const float*)d_in[4];
  const float* Bz  = (const float*)d_in[5];
  const float* Wh  = (const float*)d_in[6];
  const float* Bh  = (const float*)d_in[7];
  const float* W   = (const float*)d_in[8];
  const float* bo  = (const float*)d_in[9];
  float* out = (float*)d_out;

  char* ws = (char*)d_ws;
  float*          h_T  = (float*)(ws);                    // 128 KiB  (h_{t} transposed [j][b])
  float*          u_T  = (float*)(ws + 131072);           // 128 KiB  (r*h transposed [m][b])
  float*          z_N  = (float*)(ws + 262144);           // 128 KiB  (z [b][j])
  unsigned short* Habf = (unsigned short*)(ws + 393216);  // 8 MiB    (bf16 h history, GEMM A)
  float* XG = out;  // 50 MiB pre-projection buffer overlaid in d_out; dead before out_gemm

  proj_kernel<<<dim3(24, 128), 256, 0, stream>>>(x, emb, Wr, Br, Wz, Bz, Wh, Bh, XG);

  for (int t = 0; t < SQ; ++t) {
    gate_rz_kernel<<<256, 64, 0, stream>>>(XG, h_T, Wr, Wz, u_T, z_N, t);
    gate_h_kernel<<<128, 64, 0, stream>>>(XG, h_T, Wh, u_T, z_N, Habf, t);
  }

  ht_copy_kernel<<<128, 256, 0, stream>>>(h_T, out + 262144000ll);
  out_gemm_kernel<<<16000, 256, 0, stream>>>(Habf, W, bo, out);
}